// Round 1
// baseline (312.863 us; speedup 1.0000x reference)
//
#include <hip/hip_runtime.h>

#define B_ 64
#define T_ 1024
#define V_ 512
#define L_ 128
#define LOG2E_ 1.4426950408889634f
#define LN2_   0.6931471805599453f
#define C_ 35           // timestep rows per chunk (7 producer waves x 5 rows)
#define RS4_ 129        // row stride in f4 units (516 floats, 2064 B, keeps 16B align)
#define RSF_ 516        // row stride in floats
#define NC_ ((T_ - 1 + C_ - 1) / C_)   // 30 chunks cover t = 1..1023

typedef float f4_t __attribute__((ext_vector_type(4)));

__device__ __forceinline__ float exp2_fast(float x) { return __builtin_amdgcn_exp2f(x); }
__device__ __forceinline__ float log2_fast(float x) { return __builtin_amdgcn_logf(x); }
__device__ __forceinline__ float ldx(float v, int e) { return __builtin_amdgcn_ldexpf(v, e); }

// wave shift-up-by-1 (lane i <- lane i-1, lane0 -> 0): DPP wave_shr:1, VALU pipe
__device__ __forceinline__ float dpp_shr1_f(float x) {
    return __int_as_float(__builtin_amdgcn_update_dpp(0, __float_as_int(x), 0x138, 0xf, 0xf, true));
}
__device__ __forceinline__ int dpp_shr1_i(int x) {
    return __builtin_amdgcn_update_dpp(0, x, 0x138, 0xf, 0xf, true);
}

// One block (8 waves) per batch item.
//  wave 0   : scaled LINEAR-domain alpha recursion, 4 states/lane + state 256 on
//             lane 63, per-lane power-of-2 scale E with neighbor adoption.
//             e-values read straight from full-row LDS ring at 3 precomputed
//             offsets: col 0 (blank, broadcast), lab[2*lane], lab[2*lane+1].
//  waves1-7 : FULL-ROW coalesced staging. No gather: 2x global_load_dwordx4
//             per row (32 sector transactions vs ~170 for the old per-state
//             gather), exp2 all 512 cols (trans pipe idle), 2x ds_write_b128.
//             Rationale: warm-LLC dispatches ran at the same 102 us as cold
//             ones -> not HBM-bound; bound by gather transaction issue.
// One __syncthreads per 35-step chunk, 2-buffer ping/pong.
__global__ __launch_bounds__(512, 1) void ctc_alpha_kernel(
    const float* __restrict__ outputs, const int* __restrict__ labels,
    const int* __restrict__ out_lens, const int* __restrict__ lab_lens,
    float* __restrict__ ws, float* __restrict__ out)
{
    const int b    = blockIdx.x;
    const int tid  = threadIdx.x;
    const int wid  = tid >> 6;
    const int lane = tid & 63;

    int* cnt = (int*)ws;            // ws[0]: zeroed by hipMemsetAsync each launch
    float* losses = ws + 16;        // ws[16..79]: per-batch losses

    __shared__ f4_t  ring4[2][C_ * RS4_];   // 2 x 35 x 2064 B = 144,480 B
    __shared__ float save2[2];
    __shared__ int   saveE[2];
    __shared__ int   amLast;

    const int olen  = out_lens[b];
    const int ll    = lab_lens[b];
    const int s0q   = 2 * ll - 1;                 // odd
    const int s1q   = 2 * ll;                     // even, may be 256
    const int tlast = olen - 1;
    const int l0  = s0q >> 2, j0 = s0q & 3;
    const int l1e = (s1q == 256) ? 63 : (s1q >> 2);
    const int j1  = s1q & 3;
    const float* base = outputs + (size_t)b * T_ * V_;
    const int*   lab  = labels + b * L_;

    // ---------------- consumer setup (wave 0) ----------------
    // lane owns states 4l..4l+3; only odd states (j=1,3) can have skip.
    // e-columns for this lane: blank (0), lab[2l] (state 4l+1), lab[2l+1] (4l+3).
    float sk1 = 0.f, sk3 = 0.f;
    float v0 = 0.f, v1 = 0.f, v2 = 0.f, v3 = 0.f, vx = 0.f;  // vx: state 256 (lane63)
    int   E = 0;                                             // per-lane scale
    int   c1o = 0, c3o = 0;                                  // LDS float offsets
    const bool isl0 = (lane == 0);
    if (wid == 0) {
        __builtin_amdgcn_s_setprio(3);
        {
            int la = lab[2 * lane];         // label for state 4l+1
            int lb = lab[2 * lane + 1];     // label for state 4l+3
            c1o = la; c3o = lb;
            sk3 = (lb != la) ? 1.f : 0.f;
            if (lane >= 1) sk1 = (la != lab[2 * lane - 1]) ? 1.f : 0.f;
        }
        if (isl0) {
            v0 = exp2_fast(base[0]      * LOG2E_);       // s=0 blank
            v1 = exp2_fast(base[lab[0]] * LOG2E_);       // s=1 first label
        }
        if (tlast == 0) {
            float w0 = (j0==0)?v0:(j0==1)?v1:(j0==2)?v2:v3;
            float w1 = (s1q==256) ? vx : ((j1==0)?v0:(j1==1)?v1:(j1==2)?v2:v3);
            if (lane == l0)  { save2[0] = w0; saveE[0] = E; }
            if (lane == l1e) { save2[1] = w1; saveE[1] = E; }
        }
    } else {
        __builtin_amdgcn_s_setprio(0);
    }

    // producer: issue all 10 coalesced row loads first (full MLP), then
    // exponentiate and store full rows to the ring.
    auto produce = [&](int bb, int t0) {
        f4_t va[5], vb[5];
        #pragma unroll
        for (int m = 0; m < 5; ++m) {
            int t = t0 + (wid - 1) + 7 * m;
            const f4_t* rp = (const f4_t*)((t < T_) ? (base + (size_t)t * V_) : base);
            va[m] = rp[lane];        // floats 4*lane   .. 4*lane+3
            vb[m] = rp[lane + 64];   // floats 256+4*lane ..
        }
        #pragma unroll
        for (int m = 0; m < 5; ++m) {
            int r = (wid - 1) + 7 * m;
            int t = t0 + r;
            if (t < T_) {
                f4_t ea, eb2;
                ea.x  = exp2_fast(va[m].x * LOG2E_);
                ea.y  = exp2_fast(va[m].y * LOG2E_);
                ea.z  = exp2_fast(va[m].z * LOG2E_);
                ea.w  = exp2_fast(va[m].w * LOG2E_);
                eb2.x = exp2_fast(vb[m].x * LOG2E_);
                eb2.y = exp2_fast(vb[m].y * LOG2E_);
                eb2.z = exp2_fast(vb[m].z * LOG2E_);
                eb2.w = exp2_fast(vb[m].w * LOG2E_);
                f4_t* d4 = &ring4[bb][r * RS4_];
                d4[lane]      = ea;      // conflict-free: consecutive 16B/lane
                d4[lane + 64] = eb2;
            }
        }
    };

    // one recursion step with per-lane scale adoption
    auto step = [&](float eb, float e1, float e3) {
        float up1 = dpp_shr1_f(v3);           // state 4l-1 (lane0 -> 0)
        int   upE = dpp_shr1_i(E);
        upE = isl0 ? E : upE;                 // lane0: keep own scale

        // branchless scale align: shift the smaller side down (exact)
        int d    = upE - E;
        int mpos = (d > 0) ? d : 0;           // max(d,0)
        int sin  = (d < 0) ? d : 0;           // min(d,0)
        int sown = -mpos;
        E += mpos;
        v0 = ldx(v0, sown); v1 = ldx(v1, sown); v2 = ldx(v2, sown);
        v3 = ldx(v3, sown); vx = ldx(vx, sown);
        up1 = ldx(up1, sin);

        float n0 = (v0 + up1) * eb;                    // even: no skip, blank col
        float n1 = fmaf(sk1, up1, v1 + v0) * e1;       // skip from 4l-1 = up1
        float n2 = (v2 + v1) * eb;                     // even: no skip, blank col
        float n3 = fmaf(sk3, v1, v3 + v2) * e3;        // skip from 4l+1 = v1
        vx = (vx + v3) * eb;                           // state 256 (valid on lane63)
        v0 = n0; v1 = n1; v2 = n2; v3 = n3;
    };

    // per-lane renorm: scale own max to ~[1,2)
    auto renorm = [&]() {
        float mx = fmaxf(fmaxf(v0, v1), fmaxf(v2, v3));
        mx = fmaxf(mx, vx);
        int ex = (__float_as_int(mx) >> 23) - 126;     // 0 lanes: ex = -126
        v0 = ldx(v0, -ex); v1 = ldx(v1, -ex); v2 = ldx(v2, -ex); v3 = ldx(v3, -ex);
        vx = ldx(vx, -ex);
        E += ex;
    };

    auto consume = [&](int bb, int t0) {
        const float* rf = (const float*)&ring4[bb][0];
        // 4-deep e-load pipeline (3 scalar LDS reads/row; col-0 is a broadcast)
        float ebb[4], e1b[4], e3b[4];
        #pragma unroll
        for (int i = 0; i < 4; ++i) {
            int o = i * RSF_;
            ebb[i] = rf[o]; e1b[i] = rf[o + c1o]; e3b[i] = rf[o + c3o];
        }
        bool chk = (t0 + C_ > T_) || ((unsigned)(tlast - t0) < (unsigned)C_);
        if (!chk) {
            #pragma unroll 5
            for (int r = 0; r < C_; ++r) {
                float eb = ebb[r & 3], e1 = e1b[r & 3], e3 = e3b[r & 3];
                if (r + 4 < C_) {
                    int o = (r + 4) * RSF_;
                    ebb[r & 3] = rf[o]; e1b[r & 3] = rf[o + c1o]; e3b[r & 3] = rf[o + c3o];
                }
                step(eb, e1, e3);
                if ((r & 3) == 3) renorm();
            }
        } else {
            for (int r = 0; r < C_; ++r) {
                int t = t0 + r;
                if (t >= T_) break;
                float eb = ebb[r & 3], e1 = e1b[r & 3], e3 = e3b[r & 3];
                if (r + 4 < C_) {
                    int o = (r + 4) * RSF_;
                    ebb[r & 3] = rf[o]; e1b[r & 3] = rf[o + c1o]; e3b[r & 3] = rf[o + c3o];
                }
                step(eb, e1, e3);
                if ((r & 3) == 3) renorm();
                if (t == tlast) {
                    float w0 = (j0==0)?v0:(j0==1)?v1:(j0==2)?v2:v3;
                    float w1 = (s1q==256) ? vx : ((j1==0)?v0:(j1==1)?v1:(j1==2)?v2:v3);
                    if (lane == l0)  { save2[0] = w0; saveE[0] = E; }
                    if (lane == l1e) { save2[1] = w1; saveE[1] = E; }
                }
            }
        }
    };

    // ---------------- pipeline ----------------
    if (wid > 0) produce(0, 1);
    __syncthreads();
    for (int c = 0; c < NC_; ++c) {
        if (wid > 0) {
            if (c + 1 < NC_) produce((c + 1) & 1, 1 + (c + 1) * C_);
        } else {
            consume(c & 1, 1 + c * C_);
        }
        __syncthreads();
    }

    // ---------------- fused finish: per-batch loss + last-block mean ----------
    if (tid == 0) {
        float lx = log2_fast(save2[0]) + (float)saveE[0];
        float ly = log2_fast(save2[1]) + (float)saveE[1];
        float m  = fmaxf(lx, ly);
        float lik2 = m + log2_fast(exp2_fast(lx - m) + exp2_fast(ly - m));
        float loss = -(lik2 * LN2_) / (float)ll;
        __hip_atomic_store(&losses[b], loss, __ATOMIC_RELAXED, __HIP_MEMORY_SCOPE_AGENT);
        int old = __hip_atomic_fetch_add(cnt, 1, __ATOMIC_ACQ_REL, __HIP_MEMORY_SCOPE_AGENT);
        amLast = (old == B_ - 1);
    }
    __syncthreads();
    if (amLast && wid == 0) {
        float v = __hip_atomic_load(&losses[lane], __ATOMIC_RELAXED, __HIP_MEMORY_SCOPE_AGENT);
        #pragma unroll
        for (int o = 32; o > 0; o >>= 1) v += __shfl_down(v, o);
        if (lane == 0) out[0] = v * (1.0f / B_);
    }
}

extern "C" void kernel_launch(void* const* d_in, const int* in_sizes, int n_in,
                              void* d_out, int out_size, void* d_ws, size_t ws_size,
                              hipStream_t stream) {
    const float* outputs  = (const float*)d_in[0];
    const int*   labels   = (const int*)d_in[1];
    const int*   out_lens = (const int*)d_in[2];
    const int*   lab_lens = (const int*)d_in[3];

    (void)hipMemsetAsync(d_ws, 0, 64, stream);   // zero the completion counter
    ctc_alpha_kernel<<<B_, 512, 0, stream>>>(outputs, labels, out_lens, lab_lens,
                                             (float*)d_ws, (float*)d_out);
}

// Round 2
// 234.306 us; speedup vs baseline: 1.3353x; 1.3353x over previous
//
#include <hip/hip_runtime.h>

#define B_ 64
#define T_ 1024
#define V_ 512
#define L_ 128
#define LOG2E_ 1.4426950408889634f
#define LN2_   0.6931471805599453f
#define C_ 56           // timestep rows per chunk (7 producer waves x 8 rows)
#define RW4_ 65         // row stride in f4 units (260 floats, 1040 B) - R0-proven conflict-free
#define NC_ ((T_ - 1 + C_ - 1) / C_)   // 19 chunks cover t = 1..1023

typedef float f4_t __attribute__((ext_vector_type(4)));

__device__ __forceinline__ float exp2_fast(float x) { return __builtin_amdgcn_exp2f(x); }
__device__ __forceinline__ float log2_fast(float x) { return __builtin_amdgcn_logf(x); }
__device__ __forceinline__ float ldx(float v, int e) { return __builtin_amdgcn_ldexpf(v, e); }

// wave shift-up-by-1 (lane i <- lane i-1, lane0 -> 0): DPP wave_shr:1, VALU pipe
__device__ __forceinline__ float dpp_shr1_f(float x) {
    return __int_as_float(__builtin_amdgcn_update_dpp(0, __float_as_int(x), 0x138, 0xf, 0xf, true));
}
__device__ __forceinline__ int dpp_shr1_i(int x) {
    return __builtin_amdgcn_update_dpp(0, x, 0x138, 0xf, 0xf, true);
}

// One block (8 waves) per batch item.
//  wave 0   : scaled LINEAR-domain alpha recursion, 4 states/lane + state 256 on
//             lane 63, per-lane power-of-2 scale E with neighbor adoption.
//             Per step ONE conflict-free ds_read_b128: (eb, e1, e3, pad) where
//             eb = exp(blank col) feeds ALL even states (incl. state 256),
//             e1 = exp(col lab[2l]) state 4l+1, e3 = exp(col lab[2l+1]) state 4l+3.
//             2-deep period-2 prefetch ring + even unroll (R1 lesson: period-4
//             ring under unroll-5 broke the SW pipeline; random-col b32 reads
//             put 609K bank-conflict cycles on the consumer chain).
//  waves1-7 : gather exactly 3 cols/row (col 0 is a 1-transaction uniform load;
//             R0 redundantly re-gathered the blank col for all 128 even states:
//             ~120 sectors/row -> ~58 now), exp2 x3, pack one f4 store/lane.
// Math is bit-identical to the 102us R0 kernel. One __syncthreads per chunk.
__global__ __launch_bounds__(512, 1) void ctc_alpha_kernel(
    const float* __restrict__ outputs, const int* __restrict__ labels,
    const int* __restrict__ out_lens, const int* __restrict__ lab_lens,
    float* __restrict__ ws, float* __restrict__ out)
{
    const int b    = blockIdx.x;
    const int tid  = threadIdx.x;
    const int wid  = tid >> 6;
    const int lane = tid & 63;

    int* cnt = (int*)ws;            // ws[0]: zeroed by hipMemsetAsync each launch
    float* losses = ws + 16;        // ws[16..79]: per-batch losses

    __shared__ f4_t  ring4[2][C_ * RW4_];   // 2 x 56 x 1040 B = 116,480 B
    __shared__ float save2[2];
    __shared__ int   saveE[2];
    __shared__ int   amLast;

    const int olen  = out_lens[b];
    const int ll    = lab_lens[b];
    const int s0q   = 2 * ll - 1;                 // odd
    const int s1q   = 2 * ll;                     // even, may be 256
    const int tlast = olen - 1;
    const int l0  = s0q >> 2, j0 = s0q & 3;
    const int l1e = (s1q == 256) ? 63 : (s1q >> 2);
    const int j1  = s1q & 3;
    const float* base = outputs + (size_t)b * T_ * V_;
    const int*   lab  = labels + b * L_;

    // per-lane label columns (used by producers for the gather; lane l of each
    // producer wave stages for consumer lane l)
    const int cA = lab[2 * lane];         // col for state 4l+1
    const int cB = lab[2 * lane + 1];     // col for state 4l+3

    // ---------------- consumer setup (wave 0) ----------------
    float sk1 = 0.f, sk3 = 0.f;
    float v0 = 0.f, v1 = 0.f, v2 = 0.f, v3 = 0.f, vx = 0.f;  // vx: state 256 (lane63)
    int   E = 0;                                             // per-lane scale
    const bool isl0 = (lane == 0);
    if (wid == 0) {
        __builtin_amdgcn_s_setprio(3);
        sk3 = (cB != cA) ? 1.f : 0.f;
        if (lane >= 1) sk1 = (cA != lab[2 * lane - 1]) ? 1.f : 0.f;
        if (isl0) {
            v0 = exp2_fast(base[0]      * LOG2E_);       // s=0 blank
            v1 = exp2_fast(base[lab[0]] * LOG2E_);       // s=1 first label
        }
        if (tlast == 0) {
            float w0 = (j0==0)?v0:(j0==1)?v1:(j0==2)?v2:v3;
            float w1 = (s1q==256) ? vx : ((j1==0)?v0:(j1==1)?v1:(j1==2)?v2:v3);
            if (lane == l0)  { save2[0] = w0; saveE[0] = E; }
            if (lane == l1e) { save2[1] = w1; saveE[1] = E; }
        }
    } else {
        __builtin_amdgcn_s_setprio(0);
    }

    // producer: all 24 gathers issue before any use (full MLP), then
    // pre-exponentiate and pack one f4 per lane per row.
    auto produce = [&](int bb, int t0) {
        float gb[8], g1[8], g3[8];
        #pragma unroll
        for (int m = 0; m < 8; ++m) {
            int t = t0 + (wid - 1) + 7 * m;
            const float* rp = (t < T_) ? (base + (size_t)t * V_) : base;
            gb[m] = rp[0];      // blank col: uniform addr -> 1 transaction
            g1[m] = rp[cA];
            g3[m] = rp[cB];
        }
        #pragma unroll
        for (int m = 0; m < 8; ++m) {
            int r = (wid - 1) + 7 * m;
            int t = t0 + r;
            if (t < T_) {
                f4_t e;
                e.x = exp2_fast(gb[m] * LOG2E_);
                e.y = exp2_fast(g1[m] * LOG2E_);
                e.z = exp2_fast(g3[m] * LOG2E_);
                e.w = 0.f;
                ring4[bb][r * RW4_ + lane] = e;   // 16B/lane contiguous: conflict-free
            }
        }
    };

    // one recursion step with per-lane scale adoption
    auto step = [&](f4_t e) {
        float up1 = dpp_shr1_f(v3);           // state 4l-1 (lane0 -> 0)
        int   upE = dpp_shr1_i(E);
        upE = isl0 ? E : upE;                 // lane0: keep own scale

        // branchless scale align: shift the smaller side down (exact)
        int d    = upE - E;
        int mpos = (d > 0) ? d : 0;           // max(d,0)
        int sin  = (d < 0) ? d : 0;           // min(d,0)
        int sown = -mpos;
        E += mpos;
        v0 = ldx(v0, sown); v1 = ldx(v1, sown); v2 = ldx(v2, sown);
        v3 = ldx(v3, sown); vx = ldx(vx, sown);
        up1 = ldx(up1, sin);

        float n0 = (v0 + up1) * e.x;                   // even: no skip, blank col
        float n1 = fmaf(sk1, up1, v1 + v0) * e.y;      // skip from 4l-1 = up1
        float n2 = (v2 + v1) * e.x;                    // even: no skip, blank col
        float n3 = fmaf(sk3, v1, v3 + v2) * e.z;       // skip from 4l+1 = v1
        vx = (vx + v3) * e.x;                          // state 256 (blank col too)
        v0 = n0; v1 = n1; v2 = n2; v3 = n3;
    };

    // per-lane renorm: scale own max to ~[1,2)
    auto renorm = [&]() {
        float mx = fmaxf(fmaxf(v0, v1), fmaxf(v2, v3));
        mx = fmaxf(mx, vx);
        int ex = (__float_as_int(mx) >> 23) - 126;     // 0 lanes: ex = -126
        v0 = ldx(v0, -ex); v1 = ldx(v1, -ex); v2 = ldx(v2, -ex); v3 = ldx(v3, -ex);
        vx = ldx(vx, -ex);
        E += ex;
    };

    auto consume = [&](int bb, int t0) {
        const f4_t* rp4 = &ring4[bb][lane];
        // 2-deep period-2 e-load pipeline (matches even unroll: residue is
        // compile-time constant -> stays in registers, clean lgkmcnt pipeline)
        f4_t eb2[2];
        eb2[0] = rp4[0];
        eb2[1] = rp4[RW4_];

        bool chk = (t0 + C_ > T_) || ((unsigned)(tlast - t0) < (unsigned)C_);
        if (!chk) {
            #pragma unroll 8
            for (int r = 0; r < C_; ++r) {
                f4_t e = eb2[r & 1];
                if (r + 2 < C_) eb2[r & 1] = rp4[(r + 2) * RW4_];
                step(e);
                if ((r & 3) == 3) renorm();
            }
        } else {
            #pragma unroll 4
            for (int r = 0; r < C_; ++r) {
                int t = t0 + r;
                if (t >= T_) break;
                f4_t e = eb2[r & 1];
                if (r + 2 < C_) eb2[r & 1] = rp4[(r + 2) * RW4_];
                step(e);
                if ((r & 3) == 3) renorm();
                if (t == tlast) {
                    float w0 = (j0==0)?v0:(j0==1)?v1:(j0==2)?v2:v3;
                    float w1 = (s1q==256) ? vx : ((j1==0)?v0:(j1==1)?v1:(j1==2)?v2:v3);
                    if (lane == l0)  { save2[0] = w0; saveE[0] = E; }
                    if (lane == l1e) { save2[1] = w1; saveE[1] = E; }
                }
            }
        }
    };

    // ---------------- pipeline ----------------
    if (wid > 0) produce(0, 1);
    __syncthreads();
    for (int c = 0; c < NC_; ++c) {
        if (wid > 0) {
            if (c + 1 < NC_) produce((c + 1) & 1, 1 + (c + 1) * C_);
        } else {
            consume(c & 1, 1 + c * C_);
        }
        __syncthreads();
    }

    // ---------------- fused finish: per-batch loss + last-block mean ----------
    if (tid == 0) {
        float lx = log2_fast(save2[0]) + (float)saveE[0];
        float ly = log2_fast(save2[1]) + (float)saveE[1];
        float m  = fmaxf(lx, ly);
        float lik2 = m + log2_fast(exp2_fast(lx - m) + exp2_fast(ly - m));
        float loss = -(lik2 * LN2_) / (float)ll;
        __hip_atomic_store(&losses[b], loss, __ATOMIC_RELAXED, __HIP_MEMORY_SCOPE_AGENT);
        int old = __hip_atomic_fetch_add(cnt, 1, __ATOMIC_ACQ_REL, __HIP_MEMORY_SCOPE_AGENT);
        amLast = (old == B_ - 1);
    }
    __syncthreads();
    if (amLast && wid == 0) {
        float v = __hip_atomic_load(&losses[lane], __ATOMIC_RELAXED, __HIP_MEMORY_SCOPE_AGENT);
        #pragma unroll
        for (int o = 32; o > 0; o >>= 1) v += __shfl_down(v, o);
        if (lane == 0) out[0] = v * (1.0f / B_);
    }
}

extern "C" void kernel_launch(void* const* d_in, const int* in_sizes, int n_in,
                              void* d_out, int out_size, void* d_ws, size_t ws_size,
                              hipStream_t stream) {
    const float* outputs  = (const float*)d_in[0];
    const int*   labels   = (const int*)d_in[1];
    const int*   out_lens = (const int*)d_in[2];
    const int*   lab_lens = (const int*)d_in[3];

    (void)hipMemsetAsync(d_ws, 0, 64, stream);   // zero the completion counter
    ctc_alpha_kernel<<<B_, 512, 0, stream>>>(outputs, labels, out_lens, lab_lens,
                                             (float*)d_ws, (float*)d_out);
}